// Round 10
// baseline (455.571 us; speedup 1.0000x reference)
//
#include <hip/hip_runtime.h>
#include <hip/hip_bf16.h>
#include <math.h>

#define B_N 8192
#define D_DIM 1024
#define NTILES 2080  // 64 diag + 2016 upper-triangle off-diag

using bf16 = __hip_bfloat16;
typedef float f32x4 __attribute__((ext_vector_type(4)));
typedef __bf16 bf16x8 __attribute__((ext_vector_type(8)));

// ws layout:
//   [0, 16MB)              : Xn bf16 [8192][1024]
//   red = 16MB:
//     red + 0      .. 32KB : S[8192] f32 (sum exp(sim-10), j != i) [atomic, zeroed]
//     red + 32KB   .. 64KB : P[8192] f32 (mask row popcount)      [atomic, zeroed]
//     red + 64KB + 4       : flag u32 (mask-dtype detection)      [atomic, zeroed]
//     red + 64KB + 256     : Mpart[2080] f32 (per-block sum mask*sim)

__global__ void detect_mask_kernel(const unsigned* __restrict__ m, unsigned* __restrict__ flag) {
    // Read first 1MB as u32. u8-bool mask at ~1% density -> ~3% of words >1.
    // i32 mask -> all words in {0,1} -> flag stays 0.
    unsigned c = 0;
    for (int i = blockIdx.x * blockDim.x + threadIdx.x; i < 262144;
         i += gridDim.x * blockDim.x) {
        c += (m[i] > 1u) ? 1u : 0u;
    }
    for (int s = 1; s < 64; s <<= 1) c += __shfl_xor(c, s, 64);
    if ((threadIdx.x & 63) == 0 && c) atomicAdd(flag, c);
}

__global__ void normalize_kernel(const float* __restrict__ emb, bf16* __restrict__ xn) {
    int row = blockIdx.x;
    int t = threadIdx.x;  // 256 threads, 4 floats each
    const float4* src = (const float4*)(emb + (size_t)row * D_DIM);
    float4 v = src[t];
    float ss = v.x * v.x + v.y * v.y + v.z * v.z + v.w * v.w;
    for (int s = 1; s < 64; s <<= 1) ss += __shfl_xor(ss, s, 64);
    __shared__ float wss[4];
    if ((t & 63) == 0) wss[t >> 6] = ss;
    __syncthreads();
    float tot = wss[0] + wss[1] + wss[2] + wss[3];
    float scale = 1.0f / fmaxf(sqrtf(tot), 1e-12f);
    ushort4 o;
    o.x = __builtin_bit_cast(unsigned short, __float2bfloat16(v.x * scale));
    o.y = __builtin_bit_cast(unsigned short, __float2bfloat16(v.y * scale));
    o.z = __builtin_bit_cast(unsigned short, __float2bfloat16(v.z * scale));
    o.w = __builtin_bit_cast(unsigned short, __float2bfloat16(v.w * scale));
    *reinterpret_cast<ushort4*>(xn + (size_t)row * D_DIM + t * 4) = o;
}

// Upper-triangle tiling: 64 diag + 2016 off-diag = 2080 blocks.
// 128x128 tile, BK=64, 4 waves (2x2), each wave 64x64 = 4x4 frags of 16x16x32.
// K-loop = R7 exactly (2-barrier single-buffer + LDS XOR swizzle). Mask is
// consumed in the EPILOGUE via coalesced ballot-packing (64 lanes x 4B =
// 256B contiguous per row), replacing the serial 256MB pack_mask_kernel.
// R9 bug fixed: colE accumulation was dropped -> col-side S was zero.
__global__ __launch_bounds__(256, 2) void sim_kernel(
    const bf16* __restrict__ xn,
    const unsigned char* __restrict__ m8,
    const int* __restrict__ m32,
    const unsigned* __restrict__ flag,
    float* __restrict__ S, float* __restrict__ Pp, float* __restrict__ Mpart)
{
    __shared__ bf16 Abuf[128 * 64];
    __shared__ bf16 Bbuf[128 * 64];
    __shared__ unsigned long long Wd[4][64];  // per-wave ballot words (2KB)
    __shared__ float Mred[4];

    // XCD-aware bijective swizzle (2080 % 8 == 0 -> 260 per XCD)
    int b0 = blockIdx.x;
    int tile = (b0 & 7) * 260 + (b0 >> 3);
    int by, bx;
    bool isdiag;
    if (tile < 64) {
        by = bx = tile;
        isdiag = true;
    } else {
        int j = tile - 64;  // [0, 2016)
        int p = (int)((sqrt((double)(8 * j + 1)) + 1.0) * 0.5);
        while (p * (p - 1) / 2 > j) --p;
        while ((p + 1) * p / 2 <= j) ++p;
        int q = j - p * (p - 1) / 2;
        by = q; bx = p;  // by < bx
        isdiag = false;
    }

    int t = threadIdx.x;
    int w = t >> 6, lane = t & 63;
    int wm = w >> 1, wn = w & 1;
    int l15 = lane & 15, lg = lane >> 4;

    const bool is_u8 = (*flag != 0u);

    f32x4 acc[4][4];
#pragma unroll
    for (int i = 0; i < 4; i++)
#pragma unroll
        for (int j = 0; j < 4; j++) acc[i][j] = {0.f, 0.f, 0.f, 0.f};

    int arow0 = by << 7;
    int brow0 = bx << 7;

    // Staging geometry (R7): e = i*256 + w*64 + lane; row r = e>>3
    // (r&7 == lane>>3), dest chunk = lane&7 (linear), source chunk
    // pre-swizzled: (lane&7) ^ (lane>>3). Read side XORs the same way.
    int ebase0 = w * 64;
    int c80 = ((lane & 7) ^ (lane >> 3)) << 3;
    int rlane = (w << 3) + (lane >> 3);
    int xr = l15 & 7;

    for (int kt = 0; kt < D_DIM; kt += 64) {
#pragma unroll
        for (int i = 0; i < 4; ++i) {
            int ebase = i * 256 + ebase0;    // wave-uniform LDS base (linear dest)
            int r = i * 32 + rlane;
            const bf16* gA = xn + (size_t)(arow0 + r) * D_DIM + kt + c80;
            const bf16* gB = xn + (size_t)(brow0 + r) * D_DIM + kt + c80;
            char* lA = (char*)Abuf + (size_t)ebase * 16;
            char* lB = (char*)Bbuf + (size_t)ebase * 16;
            __builtin_amdgcn_global_load_lds((const __attribute__((address_space(1))) void*)gA,
                                             (__attribute__((address_space(3))) void*)lA, 16, 0, 0);
            __builtin_amdgcn_global_load_lds((const __attribute__((address_space(1))) void*)gB,
                                             (__attribute__((address_space(3))) void*)lB, 16, 0, 0);
        }
        __syncthreads();
#pragma unroll
        for (int kk = 0; kk < 2; ++kk) {
            bf16x8 a[4], b[4];
#pragma unroll
            for (int f = 0; f < 4; ++f) {
                int ca = (((kk << 2) | lg) ^ xr) << 3;  // swizzled chunk
                a[f] = *reinterpret_cast<const bf16x8*>(Abuf + (wm * 64 + f * 16 + l15) * 64 + ca);
                b[f] = *reinterpret_cast<const bf16x8*>(Bbuf + (wn * 64 + f * 16 + l15) * 64 + ca);
            }
#pragma unroll
            for (int fm = 0; fm < 4; ++fm)
#pragma unroll
                for (int fn = 0; fn < 4; ++fn)
                    acc[fm][fn] = __builtin_amdgcn_mfma_f32_16x16x32_bf16(a[fm], b[fn], acc[fm][fn], 0, 0, 0);
        }
        __syncthreads();
    }

    // ---- Epilogue ----
    // C/D layout: col = l15, row = lg*4 + reg (within 16x16 frag).
    //
    // Phase A (row-side): for each of this wave's 64 rows gr, all 64 lanes
    // load mask[gr][col-slice] coalesced (256B contiguous) and __ballot into
    // a 64-bit word; lane r keeps word r; one ds_write parks all 64 words.
    {
        unsigned long long myW = 0;
#pragma unroll
        for (int rb = 0; rb < 8; ++rb) {
            bool v[8];
#pragma unroll
            for (int k = 0; k < 8; ++k) {
                int gr = arow0 + wm * 64 + rb * 8 + k;
                size_t off = (size_t)gr * B_N + brow0 + wn * 64 + lane;
                v[k] = is_u8 ? (m8[off] != 0) : (m32[off] != 0);
            }
#pragma unroll
            for (int k = 0; k < 8; ++k) {
                unsigned long long wc = __ballot(v[k]);
                if (lane == rb * 8 + k) myW = wc;
            }
        }
        Wd[w][lane] = myW;
    }

    float colE[4] = {0.f, 0.f, 0.f, 0.f};
    float Mloc = 0.f;
#pragma unroll
    for (int fm = 0; fm < 4; ++fm) {
#pragma unroll
        for (int reg = 0; reg < 4; ++reg) {
            int lr = fm * 16 + lg * 4 + reg;          // row within wave tile
            int gr = arow0 + wm * 64 + lr;
            unsigned long long wrow = Wd[w][lr];      // broadcast within l15 group
            float E = 0.f, Pc = 0.f;
#pragma unroll
            for (int fn = 0; fn < 4; ++fn) {
                int gc = brow0 + wn * 64 + fn * 16 + l15;
                float sim = acc[fm][fn][reg] * 10.0f;
                float e = __expf(sim - 10.0f);
                if (isdiag && gr == gc) e = 0.f;
                E += e;
                if (!isdiag) colE[fn] += e;  // R9 fix: col-side exp-sums
                if ((wrow >> (fn * 16 + l15)) & 1ull) { Mloc += sim; Pc += 1.f; }
            }
            E += __shfl_xor(E, 1, 64);  Pc += __shfl_xor(Pc, 1, 64);
            E += __shfl_xor(E, 2, 64);  Pc += __shfl_xor(Pc, 2, 64);
            E += __shfl_xor(E, 4, 64);  Pc += __shfl_xor(Pc, 4, 64);
            E += __shfl_xor(E, 8, 64);  Pc += __shfl_xor(Pc, 8, 64);
            if (l15 == 0) {
                atomicAdd(&S[gr], E);
                if (Pc != 0.f) atomicAdd(&Pp[gr], Pc);
            }
        }
    }

    // Phase B (col-side, off-diag only): ballot-pack the transposed block
    // mask[gc][row-slice]; consume with all-lane-productive bit tests.
    if (!isdiag) {
        unsigned long long myW = 0;
#pragma unroll
        for (int cb = 0; cb < 8; ++cb) {
            bool v[8];
#pragma unroll
            for (int k = 0; k < 8; ++k) {
                int gc = brow0 + wn * 64 + cb * 8 + k;
                size_t off = (size_t)gc * B_N + arow0 + wm * 64 + lane;
                v[k] = is_u8 ? (m8[off] != 0) : (m32[off] != 0);
            }
#pragma unroll
            for (int k = 0; k < 8; ++k) {
                unsigned long long wc = __ballot(v[k]);
                if (lane == cb * 8 + k) myW = wc;
            }
        }
        Wd[w][lane] = myW;  // same wave: LDS ops in order, no barrier needed

#pragma unroll
        for (int fn = 0; fn < 4; ++fn) {
            unsigned long long wcol = Wd[w][fn * 16 + l15];
            float Pc = 0.f;
#pragma unroll
            for (int fm = 0; fm < 4; ++fm)
#pragma unroll
                for (int reg = 0; reg < 4; ++reg) {
                    if ((wcol >> (fm * 16 + lg * 4 + reg)) & 1ull) {
                        Mloc += acc[fm][fn][reg] * 10.0f;
                        Pc += 1.f;
                    }
                }
            float E = colE[fn];
            E += __shfl_xor(E, 16, 64);  Pc += __shfl_xor(Pc, 16, 64);
            E += __shfl_xor(E, 32, 64);  Pc += __shfl_xor(Pc, 32, 64);
            if (lg == 0) {
                int gc = brow0 + wn * 64 + fn * 16 + l15;
                atomicAdd(&S[gc], E);
                if (Pc != 0.f) atomicAdd(&Pp[gc], Pc);
            }
        }
    }

    for (int s = 1; s < 64; s <<= 1) Mloc += __shfl_xor(Mloc, s, 64);
    if (lane == 0) Mred[w] = Mloc;
    __syncthreads();
    if (t == 0) Mpart[b0] = Mred[0] + Mred[1] + Mred[2] + Mred[3];
}

__global__ void finalize_kernel(const float* __restrict__ S, const float* __restrict__ P,
                                const float* __restrict__ Mpart, float* __restrict__ out) {
    int t = threadIdx.x;  // 1024
    double a = 0.0;
    for (int i = t; i < B_N; i += 1024) {
        float lse = 10.0f + logf(S[i]);
        a += (double)P[i] * (double)lse;
    }
    for (int i = t; i < NTILES; i += 1024) a -= (double)Mpart[i];
    for (int s = 1; s < 64; s <<= 1) a += __shfl_xor(a, s, 64);
    __shared__ double sh[16];
    if ((t & 63) == 0) sh[t >> 6] = a;
    __syncthreads();
    if (t == 0) {
        double tot = 0.0;
        for (int i = 0; i < 16; ++i) tot += sh[i];
        out[0] = (float)(tot / (double)B_N);
    }
}

extern "C" void kernel_launch(void* const* d_in, const int* in_sizes, int n_in,
                              void* d_out, int out_size, void* d_ws, size_t ws_size,
                              hipStream_t stream) {
    const float* emb = (const float*)d_in[0];
    const void* mask = d_in[1];
    char* ws = (char*)d_ws;
    bf16* xn = (bf16*)ws;
    const size_t XN_BYTES = (size_t)B_N * D_DIM * 2;  // 16MB
    char* red = ws + XN_BYTES;
    float* S = (float*)red;
    float* Pp = (float*)(red + 32768);
    unsigned* flag = (unsigned*)(red + 65536 + 4);
    float* Mpart = (float*)(red + 65536 + 256);

    hipMemsetAsync(red, 0, 65536 + 16, stream);
    detect_mask_kernel<<<64, 256, 0, stream>>>((const unsigned*)mask, flag);
    normalize_kernel<<<B_N, 256, 0, stream>>>(emb, xn);
    sim_kernel<<<NTILES, 256, 0, stream>>>(xn, (const unsigned char*)mask, (const int*)mask,
                                           flag, S, Pp, Mpart);
    finalize_kernel<<<1, 1024, 0, stream>>>(S, Pp, Mpart, (float*)d_out);
}

// Round 11
// 188.879 us; speedup vs baseline: 2.4120x; 2.4120x over previous
//
#include <hip/hip_runtime.h>
#include <hip/hip_bf16.h>
#include <math.h>

#define B_N 8192
#define D_DIM 1024
#define NWORDS 128   // u64 words per mask row
#define NTILES 2080  // 64 diag + 2016 upper-triangle off-diag

using bf16 = __hip_bfloat16;
typedef float f32x4 __attribute__((ext_vector_type(4)));
typedef __bf16 bf16x8 __attribute__((ext_vector_type(8)));

// ws layout:
//   [0, 16MB)                : Xn bf16 [8192][1024]
//   [16MB, 24MB)             : maskbits u64 [8192][128]
//   red = 24MB:
//     red + 0      .. 32KB   : S[8192]  f32  (sum exp(sim-10), j != i)  [atomic, zeroed]
//     red + 32KB   .. 64KB   : P[8192]  f32  (popcount of mask row)     [written by pack]
//     red + 64KB   + 4       : flag u32  (mask-dtype detection)         [atomic, zeroed]
//     red + 64KB+256 ..      : Mpart[2080] f32 (per-block sum mask*sim) [written by sim]

__global__ void detect_mask_kernel(const unsigned* __restrict__ m, unsigned* __restrict__ flag) {
    // Read first 1MB as u32. u8-bool mask at ~1% density -> ~3% of words >1.
    // i32 mask -> all words in {0,1} -> flag stays 0.
    unsigned c = 0;
    for (int i = blockIdx.x * blockDim.x + threadIdx.x; i < 262144;
         i += gridDim.x * blockDim.x) {
        c += (m[i] > 1u) ? 1u : 0u;
    }
    for (int s = 1; s < 64; s <<= 1) c += __shfl_xor(c, s, 64);
    if ((threadIdx.x & 63) == 0 && c) atomicAdd(flag, c);
}

// Fused: block b packs mask rows {2b, 2b+1} into bits (1 u64 word/thread,
// uint4 vector loads) AND L2-normalizes embedding rows {2b, 2b+1} -> bf16.
// Both parts are HBM-BW-bound; fusing pipelines 256MB + 32MB of reads in
// one dispatch (saves ~8us of serial normalize + a launch).
__global__ void norm_pack_kernel(const float* __restrict__ emb, bf16* __restrict__ xn,
                                 const unsigned char* __restrict__ m8,
                                 const int* __restrict__ m32,
                                 const unsigned* __restrict__ flag,
                                 unsigned long long* __restrict__ bits,
                                 float* __restrict__ P) {
    const bool is_u8 = (*flag != 0u);
    int tid = threadIdx.x;
    // ---- pack: one u64 word per thread (64 mask elements) ----
    size_t w = (size_t)blockIdx.x * 256 + tid;
    unsigned long long word = 0;
    if (is_u8) {
        const uint4* src = (const uint4*)(m8 + w * 64);
#pragma unroll
        for (int q = 0; q < 4; ++q) {
            uint4 v = src[q];
            unsigned cs[4] = {v.x, v.y, v.z, v.w};
#pragma unroll
            for (int c = 0; c < 4; ++c) {
                unsigned u = ((cs[c] & 0x7F7F7F7Fu) + 0x7F7F7F7Fu) | cs[c];
                u &= 0x80808080u;
                unsigned nib = ((u >> 7) & 1u) | ((u >> 14) & 2u) | ((u >> 21) & 4u) | ((u >> 28) & 8u);
                word |= (unsigned long long)nib << ((q * 4 + c) * 4);
            }
        }
    } else {
        const uint4* src = (const uint4*)(m32 + w * 64);
#pragma unroll
        for (int q = 0; q < 16; ++q) {
            uint4 v = src[q];
            unsigned nib = (unsigned)(v.x != 0) | ((unsigned)(v.y != 0) << 1) |
                           ((unsigned)(v.z != 0) << 2) | ((unsigned)(v.w != 0) << 3);
            word |= (unsigned long long)nib << (q * 4);
        }
    }
    bits[w] = word;
    float pc = (float)__popcll(word);
    for (int s = 1; s < 64; s <<= 1) pc += __shfl_xor(pc, s, 64);
    __shared__ float wsum[4];
    if ((tid & 63) == 0) wsum[tid >> 6] = pc;
    __syncthreads();
    if (tid == 0)   P[blockIdx.x * 2]     = wsum[0] + wsum[1];
    if (tid == 128) P[blockIdx.x * 2 + 1] = wsum[2] + wsum[3];

    // ---- normalize rows 2b, 2b+1 (256 threads x float4 each) ----
    __shared__ float wss[4];
#pragma unroll
    for (int rr = 0; rr < 2; ++rr) {
        int row = blockIdx.x * 2 + rr;
        const float4* src = (const float4*)(emb + (size_t)row * D_DIM);
        float4 v = src[tid];
        float ss = v.x * v.x + v.y * v.y + v.z * v.z + v.w * v.w;
        for (int s = 1; s < 64; s <<= 1) ss += __shfl_xor(ss, s, 64);
        __syncthreads();  // protect wss reuse across rr
        if ((tid & 63) == 0) wss[tid >> 6] = ss;
        __syncthreads();
        float tot = wss[0] + wss[1] + wss[2] + wss[3];
        float scale = 1.0f / fmaxf(sqrtf(tot), 1e-12f);
        ushort4 o;
        o.x = __builtin_bit_cast(unsigned short, __float2bfloat16(v.x * scale));
        o.y = __builtin_bit_cast(unsigned short, __float2bfloat16(v.y * scale));
        o.z = __builtin_bit_cast(unsigned short, __float2bfloat16(v.z * scale));
        o.w = __builtin_bit_cast(unsigned short, __float2bfloat16(v.w * scale));
        *reinterpret_cast<ushort4*>(xn + (size_t)row * D_DIM + tid * 4) = o;
    }
}

// Upper-triangle tiling: 64 diag + 2016 off-diag = 2080 blocks.
// 128x128 tile, BK=64, 4 waves (2x2), each wave 64x64 = 4x4 frags of 16x16x32.
// R7 verbatim: single-buffer 2-barrier K-loop + LDS XOR swizzle (source
// pre-swizzle + matching ds_read XOR; conflicts ~0), epilogue reads packed
// mask bits. (R8's deep pipeline and R6/R10's in-sim mask reads all
// regressed; this is the best-known structure.)
__global__ __launch_bounds__(256, 2) void sim_kernel(
    const bf16* __restrict__ xn,
    const unsigned long long* __restrict__ mbits,
    float* __restrict__ S, float* __restrict__ Mpart)
{
    __shared__ bf16 Abuf[128 * 64];
    __shared__ bf16 Bbuf[128 * 64];
    __shared__ float Mred[4];

    // XCD-aware bijective swizzle (2080 % 8 == 0 -> 260 per XCD)
    int b0 = blockIdx.x;
    int tile = (b0 & 7) * 260 + (b0 >> 3);
    int by, bx;
    bool isdiag;
    if (tile < 64) {
        by = bx = tile;
        isdiag = true;
    } else {
        int j = tile - 64;  // [0, 2016)
        int p = (int)((sqrt((double)(8 * j + 1)) + 1.0) * 0.5);
        while (p * (p - 1) / 2 > j) --p;
        while ((p + 1) * p / 2 <= j) ++p;
        int q = j - p * (p - 1) / 2;
        by = q; bx = p;  // by < bx
        isdiag = false;
    }

    int t = threadIdx.x;
    int w = t >> 6, lane = t & 63;
    int wm = w >> 1, wn = w & 1;
    int l15 = lane & 15, lg = lane >> 4;

    f32x4 acc[4][4];
#pragma unroll
    for (int i = 0; i < 4; i++)
#pragma unroll
        for (int j = 0; j < 4; j++) acc[i][j] = {0.f, 0.f, 0.f, 0.f};

    int arow0 = by << 7;
    int brow0 = bx << 7;

    // Staging geometry: e = i*256 + w*64 + lane; row r = e>>3 (r&7 == lane>>3),
    // dest chunk = lane&7 (linear), source chunk pre-swizzled (lane&7)^(lane>>3).
    int ebase0 = w * 64;
    int c80 = ((lane & 7) ^ (lane >> 3)) << 3;
    int rlane = (w << 3) + (lane >> 3);
    int xr = l15 & 7;

    for (int kt = 0; kt < D_DIM; kt += 64) {
#pragma unroll
        for (int i = 0; i < 4; ++i) {
            int ebase = i * 256 + ebase0;    // wave-uniform LDS base (linear dest)
            int r = i * 32 + rlane;
            const bf16* gA = xn + (size_t)(arow0 + r) * D_DIM + kt + c80;
            const bf16* gB = xn + (size_t)(brow0 + r) * D_DIM + kt + c80;
            char* lA = (char*)Abuf + (size_t)ebase * 16;
            char* lB = (char*)Bbuf + (size_t)ebase * 16;
            __builtin_amdgcn_global_load_lds((const __attribute__((address_space(1))) void*)gA,
                                             (__attribute__((address_space(3))) void*)lA, 16, 0, 0);
            __builtin_amdgcn_global_load_lds((const __attribute__((address_space(1))) void*)gB,
                                             (__attribute__((address_space(3))) void*)lB, 16, 0, 0);
        }
        __syncthreads();
#pragma unroll
        for (int kk = 0; kk < 2; ++kk) {
            bf16x8 a[4], b[4];
#pragma unroll
            for (int f = 0; f < 4; ++f) {
                int ca = (((kk << 2) | lg) ^ xr) << 3;  // swizzled chunk
                a[f] = *reinterpret_cast<const bf16x8*>(Abuf + (wm * 64 + f * 16 + l15) * 64 + ca);
                b[f] = *reinterpret_cast<const bf16x8*>(Bbuf + (wn * 64 + f * 16 + l15) * 64 + ca);
            }
#pragma unroll
            for (int fm = 0; fm < 4; ++fm)
#pragma unroll
                for (int fn = 0; fn < 4; ++fn)
                    acc[fm][fn] = __builtin_amdgcn_mfma_f32_16x16x32_bf16(a[fm], b[fn], acc[fm][fn], 0, 0, 0);
        }
        __syncthreads();
    }

    // ---- Epilogue ----
    // C/D layout: col = l15, row = lg*4 + reg (within 16x16 frag).
    float colE[4] = {0.f, 0.f, 0.f, 0.f};
    unsigned long long wcol[4] = {0, 0, 0, 0};
    if (!isdiag) {
#pragma unroll
        for (int fn = 0; fn < 4; ++fn) {
            int gc = brow0 + wn * 64 + fn * 16 + l15;
            wcol[fn] = mbits[(size_t)gc * NWORDS + by * 2 + wm];
        }
    }

    float Mloc = 0.f;
#pragma unroll
    for (int fm = 0; fm < 4; ++fm) {
#pragma unroll
        for (int reg = 0; reg < 4; ++reg) {
            int lr = fm * 16 + lg * 4 + reg;          // row within wave tile
            int gr = arow0 + wm * 64 + lr;
            unsigned long long wrow = mbits[(size_t)gr * NWORDS + bx * 2 + wn];
            float E = 0.f;
#pragma unroll
            for (int fn = 0; fn < 4; ++fn) {
                int gc = brow0 + wn * 64 + fn * 16 + l15;
                float sim = acc[fm][fn][reg] * 10.0f;
                float e = __expf(sim - 10.0f);
                if (isdiag && gr == gc) e = 0.f;
                E += e;
                if ((wrow >> (fn * 16 + l15)) & 1ull) Mloc += sim;
                if (!isdiag) {
                    colE[fn] += e;
                    if ((wcol[fn] >> lr) & 1ull) Mloc += sim;
                }
            }
            E += __shfl_xor(E, 1, 64);
            E += __shfl_xor(E, 2, 64);
            E += __shfl_xor(E, 4, 64);
            E += __shfl_xor(E, 8, 64);
            if (l15 == 0) atomicAdd(&S[gr], E);
        }
    }

    if (!isdiag) {
#pragma unroll
        for (int fn = 0; fn < 4; ++fn) {
            float E = colE[fn];
            E += __shfl_xor(E, 16, 64);
            E += __shfl_xor(E, 32, 64);
            if (lg == 0) atomicAdd(&S[brow0 + wn * 64 + fn * 16 + l15], E);
        }
    }

    for (int s = 1; s < 64; s <<= 1) Mloc += __shfl_xor(Mloc, s, 64);
    if (lane == 0) Mred[w] = Mloc;
    __syncthreads();
    if (t == 0) Mpart[b0] = Mred[0] + Mred[1] + Mred[2] + Mred[3];
}

__global__ void finalize_kernel(const float* __restrict__ S, const float* __restrict__ P,
                                const float* __restrict__ Mpart, float* __restrict__ out) {
    int t = threadIdx.x;  // 1024
    double a = 0.0;
    for (int i = t; i < B_N; i += 1024) {
        float lse = 10.0f + logf(S[i]);
        a += (double)P[i] * (double)lse;
    }
    for (int i = t; i < NTILES; i += 1024) a -= (double)Mpart[i];
    for (int s = 1; s < 64; s <<= 1) a += __shfl_xor(a, s, 64);
    __shared__ double sh[16];
    if ((t & 63) == 0) sh[t >> 6] = a;
    __syncthreads();
    if (t == 0) {
        double tot = 0.0;
        for (int i = 0; i < 16; ++i) tot += sh[i];
        out[0] = (float)(tot / (double)B_N);
    }
}

extern "C" void kernel_launch(void* const* d_in, const int* in_sizes, int n_in,
                              void* d_out, int out_size, void* d_ws, size_t ws_size,
                              hipStream_t stream) {
    const float* emb = (const float*)d_in[0];
    const void* mask = d_in[1];
    char* ws = (char*)d_ws;
    bf16* xn = (bf16*)ws;
    const size_t XN_BYTES = (size_t)B_N * D_DIM * 2;              // 16MB
    unsigned long long* mbits = (unsigned long long*)(ws + XN_BYTES);
    const size_t MB_BYTES = (size_t)B_N * NWORDS * 8;             // 8MB
    char* red = ws + XN_BYTES + MB_BYTES;
    float* S = (float*)red;
    float* P = (float*)(red + 32768);
    unsigned* flag = (unsigned*)(red + 65536 + 4);
    float* Mpart = (float*)(red + 65536 + 256);

    hipMemsetAsync(red, 0, 65536 + 16, stream);
    detect_mask_kernel<<<64, 256, 0, stream>>>((const unsigned*)mask, flag);
    norm_pack_kernel<<<4096, 256, 0, stream>>>(emb, xn, (const unsigned char*)mask,
                                               (const int*)mask, flag, mbits, P);
    sim_kernel<<<NTILES, 256, 0, stream>>>(xn, mbits, S, Mpart);
    finalize_kernel<<<1, 1024, 0, stream>>>(S, P, Mpart, (float*)d_out);
}